// Round 12
// baseline (117.338 us; speedup 1.0000x reference)
//
#include <hip/hip_runtime.h>
#include <hip/hip_fp16.h>

// NeuronToSpatialGrid R14: prep rewritten (LDS-free wave-transpose, 64-deep MLP,
// imm-offset loads) — R9 profile showed prep at 58.9us for ~5us of work, and
// total-minus-gemm has been a constant ~64us all session. GEMM = R13 verbatim
// (best measured: 53.6us).

typedef __attribute__((ext_vector_type(8))) _Float16 half8;
typedef __attribute__((ext_vector_type(2))) _Float16 half2v;
typedef __attribute__((ext_vector_type(4))) float floatx4;
typedef __attribute__((ext_vector_type(16))) float floatx16;

#define NB 4
#define NN 4096
#define NE 256
#define NP 4096

#if defined(__has_builtin)
#if __has_builtin(__builtin_amdgcn_fdot2)
#define HAVE_FDOT2 1
#endif
#endif

__device__ inline float sum8(half8 v, float s) {
#ifdef HAVE_FDOT2
    half2v one; one[0] = (_Float16)1.0f; one[1] = (_Float16)1.0f;
    half2v* p = (half2v*)&v;
#pragma unroll
    for (int j = 0; j < 4; j++) s = __builtin_amdgcn_fdot2(p[j], one, s, false);
#else
#pragma unroll
    for (int j = 0; j < 8; j++) s += (float)v[j];
#endif
    return s;
}

#define MFMA32(a, bb, c) __builtin_amdgcn_mfma_f32_32x32x16_f16(a, bb, c, 0, 0, 0)

// ---------- prep v2:
// blocks [0,256): LDS-free transpose. wave-slot ws = bb*4+wave = (b*256+kb);
//   lane l reads F rows kb*16+(l>>5)*8+j, col eb*32+(l&31) for eb,j in 0..7
//   (one VGPR base + imm offsets eb*128+j*1024 bytes; each instr = 2x128B segs),
//   writes frag (((b*256+kb)*8+eb)*64+l)*8+j as 8 contiguous uint4 stores.
// blocks [256,1280): EY frag order (verbatim mapping):
//   idx = (((b*256+kb)*2+rt)*64+l)*8+j = exp(-50*(r/63-y_k)^2),
//   r = rt*32+(l&31), k = kb*16+(l>>5)*8+j
__global__ __launch_bounds__(256, 2) void prep(const float* __restrict__ in,
                                               const float* __restrict__ pos,
                                               __half* __restrict__ ft,
                                               __half* __restrict__ EYf) {
    const int bb  = blockIdx.x;
    const int tid = threadIdx.x;
    if (bb < 256) {
        const int wave = tid >> 6, l = tid & 63;
        const int ws = bb * 4 + wave;          // = b*256 + kb
        const int b  = ws >> 8, kb = ws & 255;
        const float* src = in + (((size_t)(b * NN + kb * 16 + ((l >> 5) << 3))) << 8) + (l & 31);
        float v[8][8];
#pragma unroll
        for (int eb = 0; eb < 8; ++eb)
#pragma unroll
            for (int j = 0; j < 8; ++j)
                v[eb][j] = src[eb * 32 + j * 256];
        __half* dst = ft + (size_t)ws * 4096 + l * 8;   // frag base (ws*8+eb)*512
#pragma unroll
        for (int eb = 0; eb < 8; ++eb) {
            __half hh[8];
#pragma unroll
            for (int j = 0; j < 8; ++j) hh[j] = __float2half_rn(v[eb][j]);
            *(uint4*)(dst + eb * 512) = *(const uint4*)hh;
        }
    } else {
        const int base = (bb - 256) * 1024 + tid * 4;
        const int j0 = base & 7;
        const int l  = (base >> 3) & 63;
        const int rt = (base >> 9) & 1;
        const int kb = (base >> 10) & 255;
        const int b  = base >> 18;
        const int r  = rt * 32 + (l & 31);
        const int k0 = kb * 16 + ((l >> 5) << 3) + j0;
        const float ry = (float)r * (1.0f / 63.0f);
        __half hh[4];
#pragma unroll
        for (int jj = 0; jj < 4; jj++) {
            const float y = pos[((size_t)b * NN + k0 + jj) * 2 + 1];
            const float d = ry - y;
            hh[jj] = __float2half_rn(__expf(d * d * -50.0f));
        }
        *(uint2*)&EYf[base] = *(const uint2*)hh;
    }
}

// ---------- fused GEMM (R13 verbatim, best measured). 512 blocks x 512 thr
// (2 blocks/CU, 16 waves/CU). Wave (g,kw): 64m x 64e tile, k-slice kw of each
// K-64 round. Operands from global/L2 + ex from LDS, register double-buffered.
// NO barrier in the loop.
__global__ __launch_bounds__(512, 4) void nw_gemm(const __half* __restrict__ FT,
                                                  const __half* __restrict__ EYf,
                                                  const float* __restrict__ pos,
                                                  float* __restrict__ out) {
    __shared__ __align__(64) char pool[49152];   // run: exb at +24KB; epi: RS 48KB
    __shared__ float S_s[4][128];
    __shared__ float Sinv_s[128];

    __half* exb = (__half*)pool + 12288;          // 2 x 4096 halfs (16 KB)

    const int bid  = blockIdx.x;
    const int xcd  = bid & 7;            // pin (b, e-half): FT-half 1MB + EY 512KB in L2
    const int b    = xcd >> 1;
    const int etp  = xcd & 1;
    const int rest = bid >> 3;
    const int et   = etp * 2 + (rest & 1);   // e-quarter (64 e)
    const int mblk = rest >> 1;              // 0..31
    const int tid  = threadIdx.x;
    const int wave = tid >> 6, lane = tid & 63;
    const int g   = wave & 1;                // m-half (gx = 2*mblk + g)
    const int kw  = wave >> 1;               // k-quarter of each K-64 round
    const int kwo = kw * 16 + ((lane >> 5) << 3);

    // per-wave streams (frag order): kb = 4r + kw
    const __half* ftb = FT + ((size_t)(b * 256 + kw) * 8 + et * 2) * 512 + (size_t)lane * 8;
    const __half* eyb = EYf + ((size_t)b << 18) + (size_t)(kw * 2) * 512 + (size_t)lane * 8;
    const __half* exq = exb + g * 4096 + kwo;

    // ---- prologue: build ex rows (the only in-loop LDS data)
    {
        const float* pb = pos + (size_t)b * NN * 2;
        const float gx0 = (float)(mblk * 2)     * (1.0f / 63.0f);
        const float gx1 = (float)(mblk * 2 + 1) * (1.0f / 63.0f);
        for (int k = tid; k < NN; k += 512) {
            const float x = pb[2 * k];
            const float d0 = gx0 - x, d1 = gx1 - x;
            exb[k]        = __float2half_rn(__expf(d0 * d0 * -50.0f));
            exb[4096 + k] = __float2half_rn(__expf(d1 * d1 * -50.0f));
        }
    }
    __syncthreads();   // exb ready

    floatx16 acc00 = {}, acc01 = {}, acc10 = {}, acc11 = {};
    float s0 = 0.f, s1 = 0.f;

    // C-set (current) / N-set (next) register double-buffer
    half8 bfC0, bfC1, eyC0, eyC1, exC, bfN0, bfN1, eyN0, eyN1, exN;

    // load set for r=0
    bfC0 = *(const half8*)(ftb);
    bfC1 = *(const half8*)(ftb + 512);
    eyC0 = *(const half8*)(eyb);
    eyC1 = *(const half8*)(eyb + 512);
    exC  = *(const half8*)(exq);

#define ITER(r_, cb0,cb1,ce0,ce1,cx, nb0,nb1,ne0,ne1,nx) do {          \
    const int rn_ = ((r_) + 1) & 63;                                   \
    nb0 = *(const half8*)(ftb + (size_t)rn_ * 16384);                  \
    nb1 = *(const half8*)(ftb + (size_t)rn_ * 16384 + 512);            \
    ne0 = *(const half8*)(eyb + (size_t)rn_ * 4096);                   \
    ne1 = *(const half8*)(eyb + (size_t)rn_ * 4096 + 512);             \
    nx  = *(const half8*)(exq + rn_ * 64);                             \
    __builtin_amdgcn_sched_barrier(0);                                 \
    half8 a0_ = cx * ce0;                                              \
    s0 = sum8(a0_, s0);                                                \
    half8 a1_ = cx * ce1;                                              \
    s1 = sum8(a1_, s1);                                                \
    __builtin_amdgcn_s_setprio(1);                                     \
    acc00 = MFMA32(a0_, cb0, acc00);                                   \
    acc01 = MFMA32(a0_, cb1, acc01);                                   \
    acc10 = MFMA32(a1_, cb0, acc10);                                   \
    acc11 = MFMA32(a1_, cb1, acc11);                                   \
    __builtin_amdgcn_s_setprio(0);                                     \
} while (0)

    for (int t = 0; t < 32; ++t) {
        ITER(2 * t,     bfC0,bfC1,eyC0,eyC1,exC, bfN0,bfN1,eyN0,eyN1,exN);
        ITER(2 * t + 1, bfN0,bfN1,eyN0,eyN1,exN, bfC0,bfC1,eyC0,eyC1,exC);
    }
#undef ITER

    __syncthreads();   // all waves done reading exb before pool reuse

    // ---- row-sum partials (wave (g,kw) covered k = r*64 + kw*16 + hi8 + j)
    s0 += __shfl_xor(s0, 32, 64);
    s1 += __shfl_xor(s1, 32, 64);
    if (lane < 32) {
        S_s[kw][g * 64 + lane]      = s0;
        S_s[kw][g * 64 + 32 + lane] = s1;
    }

    // ---- k-split reduce through the pool (48 KB) + normalize + store
    float* RS = (float*)pool;   // 12288 floats

#define RSWRITE(A0_, A1_) do {                                                    \
        if (kw > 0) {                                                             \
            *(floatx16*)&RS[((0 * 2 + g) * 3 + (kw - 1)) * 1024 + lane * 16] = A0_; \
            *(floatx16*)&RS[((1 * 2 + g) * 3 + (kw - 1)) * 1024 + lane * 16] = A1_; \
        }                                                                         \
    } while (0)

#define RSREDUCE(A0_, A1_, RT_) do {                                              \
        if (kw == 0) {                                                            \
            _Pragma("unroll")                                                     \
            for (int qq = 0; qq < 2; qq++) {                                      \
                floatx16 a = qq ? A1_ : A0_;                                      \
                const int rb = ((qq * 2 + g) * 3) * 1024 + lane * 16;             \
                a += *(const floatx16*)&RS[rb];                                   \
                a += *(const floatx16*)&RS[rb + 1024];                            \
                a += *(const floatx16*)&RS[rb + 2048];                            \
                const int e = et * 64 + qq * 32 + (lane & 31);                    \
                float* orow = out + ((size_t)b * NE + e) * NP                     \
                                  + mblk * 128 + g * 64 + (RT_) * 32;             \
                _Pragma("unroll")                                                 \
                for (int q = 0; q < 4; ++q) {                                     \
                    const int pr = q * 8 + ((lane >> 5) << 2);                    \
                    const floatx4 sv = *(const floatx4*)&Sinv_s[g * 64 + (RT_) * 32 + pr]; \
                    floatx4 o;                                                    \
                    o.x = a[q * 4 + 0] * sv.x; o.y = a[q * 4 + 1] * sv.y;         \
                    o.z = a[q * 4 + 2] * sv.z; o.w = a[q * 4 + 3] * sv.w;         \
                    *(floatx4*)&orow[pr] = o;                                     \
                }                                                                 \
            }                                                                     \
        }                                                                         \
    } while (0)

    RSWRITE(acc00, acc01);
    __syncthreads();
    if (tid < 128)
        Sinv_s[tid] = 1.0f / (S_s[0][tid] + S_s[1][tid] + S_s[2][tid] + S_s[3][tid] + 1e-8f);
    __syncthreads();
    RSREDUCE(acc00, acc01, 0);
    __syncthreads();
    RSWRITE(acc10, acc11);
    __syncthreads();
    RSREDUCE(acc10, acc11, 1);

#undef RSWRITE
#undef RSREDUCE
}

extern "C" void kernel_launch(void* const* d_in, const int* in_sizes, int n_in,
                              void* d_out, int out_size, void* d_ws, size_t ws_size,
                              hipStream_t stream) {
    const float* feat = (const float*)d_in[0];   // [4][4096][256] f32
    const float* pos  = (const float*)d_in[1];   // [4][4096][2]  f32
    float* out = (float*)d_out;                  // [4][256][4096] f32
    __half* FT  = (__half*)d_ws;                                       // 8.39 MB (frag order)
    __half* EYf = (__half*)((char*)d_ws + 8388608);                    // +2.10 MB (frag order)

    hipLaunchKernelGGL(prep, dim3(1280), dim3(256), 0, stream, feat, pos, FT, EYf);
    hipLaunchKernelGGL(nw_gemm, dim3(512), dim3(512), 0, stream, FT, EYf, pos, out);
}